// Round 8
// baseline (75.590 us; speedup 1.0000x reference)
//
#include <hip/hip_runtime.h>

#define RNK 32
#define VOC 32000
#define BSZ 512
#define SEQ 24

#define RED_BLOCKS 4000           // 32 r-slabs x 125 chunks (2048 float4 each)
#define RED_THREADS 256

#define DEPTH 4                   // tokens in flight per chain wave
#define NSLOT 5                   // LDS slots = DEPTH+1 -> rotation never aliases

typedef const __attribute__((address_space(1))) void* as1_cvp;
typedef __attribute__((address_space(3))) void* as3_vp;

// Issue one 32x32 fp32 token matrix (4 KB) global->LDS as 4 x (64 lanes x 16B).
// LDS dest: wave-uniform base (+ implicit lane*16, linear [r][s]); global src
// per-lane: row = j*8 + lane/8 (stride VOC*RNK floats), cols (lane%8)*4..+3.
__device__ __forceinline__ void issue_matrix_load(const float* src_tok,  // core + tok*RNK
                                                  float* lds_base, int lane) {
    const int r  = lane >> 3;
    const int c0 = (lane & 7) * 4;
    #pragma unroll
    for (int j = 0; j < 4; ++j) {
        const float* src = src_tok + (size_t)(j * 8 + r) * ((size_t)VOC * RNK) + c0;
        __builtin_amdgcn_global_load_lds((as1_cvp)src, (as3_vp)(lds_base + j * 256), 16, 0, 0);
    }
}

// ---------------------------------------------------------------------------
// Phase 1: gm[r][s] = sum_v core[r][v][s]. Pure stream, zero LDS, 256-thread
// blocks at full occupancy. Per-wave register butterfly; 32 atomics per wave.
// ---------------------------------------------------------------------------
__global__ __launch_bounds__(RED_THREADS) void reduce_kernel(const float* __restrict__ core,
                                                             float* __restrict__ gm) {
    const int bid   = blockIdx.x;
    const int r     = bid & 31;
    const int chunk = bid >> 5;               // 0..124
    const int tid   = threadIdx.x;

    const float4* slab = (const float4*)(core + (size_t)r * VOC * RNK);
    const int base = chunk * 2048 + tid;      // float4 index; 32 KB per block

    float a0 = 0.f, a1 = 0.f, a2 = 0.f, a3 = 0.f;
    #pragma unroll
    for (int i = 0; i < 8; ++i) {
        float4 v = slab[base + i * 256];
        a0 += v.x; a1 += v.y; a2 += v.z; a3 += v.w;
    }

    // s-phase (tid*4)%32 = (tid&7)*4 is invariant under xor 8/16/32:
    // butterfly-combine the 8 lanes sharing each phase (register-only, per wave).
    #pragma unroll
    for (int mask = 8; mask <= 32; mask <<= 1) {
        a0 += __shfl_xor(a0, mask, 64);
        a1 += __shfl_xor(a1, mask, 64);
        a2 += __shfl_xor(a2, mask, 64);
        a3 += __shfl_xor(a3, mask, 64);
    }
    if ((tid & 63) < 8) {                     // lanes 0-7 of each wave: 32 atomics/wave
        const int s0 = (tid & 7) * 4;
        atomicAdd(&gm[r * RNK + s0 + 0], a0);
        atomicAdd(&gm[r * RNK + s0 + 1], a1);
        atomicAdd(&gm[r * RNK + s0 + 2], a2);
        atomicAdd(&gm[r * RNK + s0 + 3], a3);
    }
}

// ---------------------------------------------------------------------------
// Phase 2 (after reduce; core is L3-resident, gm final via kernel boundary):
//  - Blocks [0, BSZ): selected-token chain, depth-4 pipeline over 5 LDS slots
//    (slot (t+4)%5 != any slot in use at step t -> no WAR alias). Counted
//    vmcnt literals; issue of t+4 happens AFTER compute of t.
//  - Block BSZ: z = alpha @ gm^SEQ @ beta * BSZ.
// ---------------------------------------------------------------------------
__global__ __launch_bounds__(64) void chainz_kernel(const float* __restrict__ core,
                                                    const int* __restrict__ y,
                                                    const float* __restrict__ alpha,
                                                    const float* __restrict__ beta,
                                                    float* __restrict__ out,
                                                    const float* __restrict__ gm) {
    __shared__ float mbuf[NSLOT * 1024];      // 20 KB
    const int tid = threadIdx.x;              // == lane (1 wave/block)

    if (blockIdx.x < BSZ) {
        // ---------------- chain role: p_tilde[row] ----------------
        const int lane = tid;
        const int s    = lane & 31;
        const int half = lane >> 5;           // 0: rows 0..15, 1: rows 16..31
        const int row  = blockIdx.x;

        int   ytok  = (lane < SEQ) ? y[row * SEQ + lane] : 0;
        float state = alpha[s];               // replicated in both halves
        float betav = beta[s];

        // Drain loads above so vmcnt counts ONLY our gl_lds ops.
        asm volatile("s_waitcnt vmcnt(0)" ::: "memory");

        // prologue: tokens 0..3 into slots 0..3 (16 outstanding gl_lds)
        #pragma unroll
        for (int pt = 0; pt < DEPTH; ++pt) {
            const int tok = __shfl(ytok, pt, 64);
            issue_matrix_load(core + (size_t)tok * RNK, mbuf + pt * 1024, lane);
        }

        #pragma unroll
        for (int t = 0; t < SEQ; ++t) {       // fully unrolled -> waits are literals
            // outstanding before wait: tokens t..min(t+3, SEQ-1)
            if      (t <= SEQ - 4) asm volatile("s_waitcnt vmcnt(12)" ::: "memory");
            else if (t == SEQ - 3) asm volatile("s_waitcnt vmcnt(8)"  ::: "memory");
            else if (t == SEQ - 2) asm volatile("s_waitcnt vmcnt(4)"  ::: "memory");
            else                   asm volatile("s_waitcnt vmcnt(0)"  ::: "memory");
            __builtin_amdgcn_sched_barrier(0);

            const float* M = mbuf + (t % NSLOT) * 1024;   // bank = s -> 2-way (free)
            float a0 = 0.f, a1 = 0.f, a2 = 0.f, a3 = 0.f;
            #pragma unroll
            for (int i = 0; i < 16; i += 4) {
                a0 = fmaf(__shfl(state, half * 16 + i + 0, 64), M[(half * 16 + i + 0) * 32 + s], a0);
                a1 = fmaf(__shfl(state, half * 16 + i + 1, 64), M[(half * 16 + i + 1) * 32 + s], a1);
                a2 = fmaf(__shfl(state, half * 16 + i + 2, 64), M[(half * 16 + i + 2) * 32 + s], a2);
                a3 = fmaf(__shfl(state, half * 16 + i + 3, 64), M[(half * 16 + i + 3) * 32 + s], a3);
            }
            const float acc = (a0 + a1) + (a2 + a3);
            state = acc + __shfl_xor(acc, 32, 64);        // combine halves, re-replicate

            if (t + DEPTH < SEQ) {            // refill into a slot not in use/in flight
                const int tok = __shfl(ytok, t + DEPTH, 64);
                issue_matrix_load(core + (size_t)tok * RNK,
                                  mbuf + ((t + DEPTH) % NSLOT) * 1024, lane);
            }
        }

        float p = state * betav;
        #pragma unroll
        for (int m = 16; m >= 1; m >>= 1) p += __shfl_xor(p, m, 64);  // within-half sum
        if (lane == 0) out[row] = p;
    } else {
        // ---------------- z role: one wave ----------------
        const int s    = tid & 31;
        const int half = tid >> 5;

        float col[16];                        // this lane's half-column of m
        #pragma unroll
        for (int i = 0; i < 16; ++i) col[i] = gm[(half * 16 + i) * RNK + s];

        float v = alpha[s];
        #pragma unroll
        for (int t = 0; t < SEQ; ++t) {
            float a0 = 0.f, a1 = 0.f, a2 = 0.f, a3 = 0.f;
            #pragma unroll
            for (int i = 0; i < 16; i += 4) {
                a0 = fmaf(__shfl(v, half * 16 + i + 0, 64), col[i + 0], a0);
                a1 = fmaf(__shfl(v, half * 16 + i + 1, 64), col[i + 1], a1);
                a2 = fmaf(__shfl(v, half * 16 + i + 2, 64), col[i + 2], a2);
                a3 = fmaf(__shfl(v, half * 16 + i + 3, 64), col[i + 3], a3);
            }
            const float acc = (a0 + a1) + (a2 + a3);
            v = acc + __shfl_xor(acc, 32, 64);
        }
        float z = v * beta[s];
        #pragma unroll
        for (int m = 16; m >= 1; m >>= 1) z += __shfl_xor(z, m, 64);
        if (tid == 0) out[BSZ] = z * (float)BSZ;
    }
}

extern "C" void kernel_launch(void* const* d_in, const int* in_sizes, int n_in,
                              void* d_out, int out_size, void* d_ws, size_t ws_size,
                              hipStream_t stream) {
    const int*   y     = (const int*)d_in[0];
    const float* alpha = (const float*)d_in[1];
    const float* beta  = (const float*)d_in[2];
    const float* core  = (const float*)d_in[3];
    float* out = (float*)d_out;
    float* gm  = (float*)d_ws;                // 1024 floats of scratch

    hipMemsetAsync(gm, 0, RNK * RNK * sizeof(float), stream);
    reduce_kernel<<<RED_BLOCKS, RED_THREADS, 0, stream>>>(core, gm);
    chainz_kernel<<<BSZ + 1, 64, 0, stream>>>(core, y, alpha, beta, out, gm);
}

// Round 9
// 45.269 us; speedup vs baseline: 1.6698x; 1.6698x over previous
//
#include <hip/hip_runtime.h>

#define RNK 32
#define VOC 32000
#define BSZ 512
#define SEQ 24
#define HSEQ 12

#define LEFT_BLOCKS  BSZ
#define CHAIN_BLOCKS (2 * BSZ)            // 1024: [0,512) left, [512,1024) right
#define RED_CHUNKS 125
#define REDUCE_BLOCKS (32 * RED_CHUNKS)   // 4000
#define DEPTH 4                           // tokens in flight per chain wave
#define NSLOT 5                           // DEPTH+1 -> rotation never aliases

typedef const __attribute__((address_space(1))) void* as1_cvp;
typedef __attribute__((address_space(3))) void* as3_vp;

// Stage one 32x32 fp32 token matrix (4 KB) global->LDS, quad-XOR swizzled:
// LDS quad [r][c] holds M[r][c ^ (r&7)] (16B quads). Source-side swizzle is a
// per-lane constant: lane l covers row r = j*8 + l/8, source quad (l&7)^(l/8).
// Reads must apply the same XOR (involution; both-sides rule).
__device__ __forceinline__ void issue_matrix_load(const float* src_tok,  // core + tok*RNK
                                                  float* lds_base, int lane) {
    const int rlo = lane >> 3;                 // 0..7
    const int cq  = ((lane & 7) ^ rlo) * 4;    // swizzled source quad -> float col
    #pragma unroll
    for (int j = 0; j < 4; ++j) {
        const float* src = src_tok + (size_t)(j * 8 + rlo) * ((size_t)VOC * RNK) + cq;
        __builtin_amdgcn_global_load_lds((as1_cvp)src, (as3_vp)(lds_base + j * 256), 16, 0, 0);
    }
}

// ---------------------------------------------------------------------------
// Fused kernel, 64-thread (1-wave) blocks, 20 KB LDS.
//  - Blocks [0,512): LEFT half-chain  v = alpha * M_{t=0..11}   -> Lv[row][*]
//  - Blocks [512,1024): RIGHT half-chain w = M_{t=23..12} * beta -> Rv[row][*]
//    Both use the same duplicated-half broadcast matvec; only the precomputed
//    LDS address table and token order differ. Depth-4 gl_lds pipeline,
//    counted vmcnt literals, alias-free 5-slot rotation.
//  - Blocks [1024, ...): streaming reduce gm[r][s] = sum_v core[r][v][s].
// ---------------------------------------------------------------------------
__global__ __launch_bounds__(64) void fused_kernel(const float* __restrict__ core,
                                                   const int* __restrict__ y,
                                                   const float* __restrict__ alpha,
                                                   const float* __restrict__ beta,
                                                   float* __restrict__ Lv,
                                                   float* __restrict__ Rv,
                                                   float* __restrict__ gm) {
    __shared__ float mbuf[NSLOT * 1024];      // 20 KB (chain roles only)
    const int tid = threadIdx.x;              // == lane (1 wave/block)

    if (blockIdx.x < CHAIN_BLOCKS) {
        const bool right = blockIdx.x >= LEFT_BLOCKS;
        const int  row   = blockIdx.x - (right ? LEFT_BLOCKS : 0);
        const int  lane  = tid;
        const int  s     = lane & 31;
        const int  half  = lane >> 5;

        // token stream: left walks 0..11, right walks 23..12
        int ytok = 0;
        if (lane < HSEQ) ytok = y[row * SEQ + (right ? (SEQ - 1 - lane) : lane)];

        float state = right ? beta[s] : alpha[s];   // replicated in both halves

        // Precomputed swizzled LDS float-offsets for the 16 reads per step.
        // left : read M[r=16h+i][s]   -> la[i] = r*32 + (((s>>2)^(r&7))<<2) + (s&3)
        // right: read M[j=s][c=16h+i] -> la[i] = j*32 + (((4h+(i>>2))^(j&7))<<2) + (i&3)
        int la[16];
        if (!right) {
            #pragma unroll
            for (int i = 0; i < 16; ++i) {
                const int r = half * 16 + i;
                la[i] = r * 32 + ((((s >> 2) ^ (r & 7)) ) << 2) + (s & 3);
            }
        } else {
            #pragma unroll
            for (int i = 0; i < 16; ++i) {
                la[i] = s * 32 + ((((half * 4 + (i >> 2)) ^ (s & 7))) << 2) + (i & 3);
            }
        }

        // Drain loads above so vmcnt counts ONLY our gl_lds ops.
        asm volatile("s_waitcnt vmcnt(0)" ::: "memory");

        // prologue: tokens 0..3 into slots 0..3 (16 outstanding gl_lds)
        #pragma unroll
        for (int pt = 0; pt < DEPTH; ++pt) {
            const int tok = __shfl(ytok, pt, 64);
            issue_matrix_load(core + (size_t)tok * RNK, mbuf + pt * 1024, lane);
        }

        #pragma unroll
        for (int t = 0; t < HSEQ; ++t) {      // fully unrolled -> literal waits
            if      (t <= HSEQ - 4) asm volatile("s_waitcnt vmcnt(12)" ::: "memory");
            else if (t == HSEQ - 3) asm volatile("s_waitcnt vmcnt(8)"  ::: "memory");
            else if (t == HSEQ - 2) asm volatile("s_waitcnt vmcnt(4)"  ::: "memory");
            else                    asm volatile("s_waitcnt vmcnt(0)"  ::: "memory");
            __builtin_amdgcn_sched_barrier(0);

            const float* M = mbuf + (t % NSLOT) * 1024;
            float a0 = 0.f, a1 = 0.f, a2 = 0.f, a3 = 0.f;
            #pragma unroll
            for (int i = 0; i < 16; i += 4) {
                a0 = fmaf(__shfl(state, half * 16 + i + 0, 64), M[la[i + 0]], a0);
                a1 = fmaf(__shfl(state, half * 16 + i + 1, 64), M[la[i + 1]], a1);
                a2 = fmaf(__shfl(state, half * 16 + i + 2, 64), M[la[i + 2]], a2);
                a3 = fmaf(__shfl(state, half * 16 + i + 3, 64), M[la[i + 3]], a3);
            }
            const float acc = (a0 + a1) + (a2 + a3);
            state = acc + __shfl_xor(acc, 32, 64);    // cross-half combine, re-replicate

            if (t + DEPTH < HSEQ) {           // refill a slot neither in use nor in flight
                const int tok = __shfl(ytok, t + DEPTH, 64);
                issue_matrix_load(core + (size_t)tok * RNK,
                                  mbuf + ((t + DEPTH) % NSLOT) * 1024, lane);
            }
        }

        if (lane < 32) (right ? Rv : Lv)[row * RNK + lane] = state;
    } else {
        // ---------------- reduce role: gm[r][s] += sum_v core[r][v][s] ----------------
        const int bid   = blockIdx.x - CHAIN_BLOCKS;
        const int r     = bid & 31;
        const int chunk = bid >> 5;           // 0..124

        const float4* slab = (const float4*)(core + (size_t)r * VOC * RNK);
        const int base = chunk * 2048 + tid;  // float4 index; 32 KB per block

        float a0 = 0.f, a1 = 0.f, a2 = 0.f, a3 = 0.f;
        #pragma unroll
        for (int i = 0; i < 32; ++i) {
            float4 v = slab[base + i * 64];
            a0 += v.x; a1 += v.y; a2 += v.z; a3 += v.w;
        }

        // s-phase (tid*4)%32 = (tid&7)*4 invariant under xor 8/16/32.
        #pragma unroll
        for (int mask = 8; mask <= 32; mask <<= 1) {
            a0 += __shfl_xor(a0, mask, 64);
            a1 += __shfl_xor(a1, mask, 64);
            a2 += __shfl_xor(a2, mask, 64);
            a3 += __shfl_xor(a3, mask, 64);
        }
        if (tid < 8) {
            const int s0 = tid * 4;
            atomicAdd(&gm[r * RNK + s0 + 0], a0);
            atomicAdd(&gm[r * RNK + s0 + 1], a1);
            atomicAdd(&gm[r * RNK + s0 + 2], a2);
            atomicAdd(&gm[r * RNK + s0 + 3], a3);
        }
    }
}

// ---------------------------------------------------------------------------
// Join: p[row] = dot(Lv[row], Rv[row]); block 64 also computes z from gm.
// ---------------------------------------------------------------------------
__global__ __launch_bounds__(256) void dotz_kernel(const float* __restrict__ Lv,
                                                   const float* __restrict__ Rv,
                                                   const float* __restrict__ gm,
                                                   const float* __restrict__ alpha,
                                                   const float* __restrict__ beta,
                                                   float* __restrict__ out) {
    if (blockIdx.x < 64) {
        const int row = blockIdx.x * 8 + (threadIdx.x >> 5);   // 8 rows/block
        const int l   = threadIdx.x & 31;
        float v = Lv[row * RNK + l] * Rv[row * RNK + l];
        #pragma unroll
        for (int m = 16; m >= 1; m >>= 1) v += __shfl_xor(v, m, 64);  // stays in 32-group
        if (l == 0) out[row] = v;
    } else if (threadIdx.x < 64) {
        const int s    = threadIdx.x & 31;
        const int half = threadIdx.x >> 5;
        float col[16];
        #pragma unroll
        for (int i = 0; i < 16; ++i) col[i] = gm[(half * 16 + i) * RNK + s];
        float v = alpha[s];
        #pragma unroll
        for (int t = 0; t < SEQ; ++t) {
            float a0 = 0.f, a1 = 0.f, a2 = 0.f, a3 = 0.f;
            #pragma unroll
            for (int i = 0; i < 16; i += 4) {
                a0 = fmaf(__shfl(v, half * 16 + i + 0, 64), col[i + 0], a0);
                a1 = fmaf(__shfl(v, half * 16 + i + 1, 64), col[i + 1], a1);
                a2 = fmaf(__shfl(v, half * 16 + i + 2, 64), col[i + 2], a2);
                a3 = fmaf(__shfl(v, half * 16 + i + 3, 64), col[i + 3], a3);
            }
            const float acc = (a0 + a1) + (a2 + a3);
            v = acc + __shfl_xor(acc, 32, 64);
        }
        float z = v * beta[s];
        #pragma unroll
        for (int m = 16; m >= 1; m >>= 1) z += __shfl_xor(z, m, 64);
        if (threadIdx.x == 0) out[BSZ] = z * (float)BSZ;
    }
}

extern "C" void kernel_launch(void* const* d_in, const int* in_sizes, int n_in,
                              void* d_out, int out_size, void* d_ws, size_t ws_size,
                              hipStream_t stream) {
    const int*   y     = (const int*)d_in[0];
    const float* alpha = (const float*)d_in[1];
    const float* beta  = (const float*)d_in[2];
    const float* core  = (const float*)d_in[3];
    float* out = (float*)d_out;
    float* gm  = (float*)d_ws;                 // 1024 floats
    float* Lv  = gm + RNK * RNK;               // 512*32
    float* Rv  = Lv + BSZ * RNK;               // 512*32

    hipMemsetAsync(gm, 0, RNK * RNK * sizeof(float), stream);
    fused_kernel<<<CHAIN_BLOCKS + REDUCE_BLOCKS, 64, 0, stream>>>(
        core, y, alpha, beta, Lv, Rv, gm);
    dotz_kernel<<<65, 256, 0, stream>>>(Lv, Rv, gm, alpha, beta, out);
}